// Round 1
// 417.639 us; speedup vs baseline: 1.0020x; 1.0020x over previous
//
#include <hip/hip_runtime.h>

// 2x2 avg-pool (sum*0.5) + 2x2 nearest upsample, fp32, shape (16,256,128,128).
//
// v2: 4 columns per thread (was 8). With col4-granularity, every VMEM
// instruction's 64 lanes cover two fully-contiguous 512B row segments —
// each 64B line is requested exactly ONCE per instruction (the previous
// 8-col layout touched every line from TWO instructions: 16B lanes at 32B
// stride), halving TA/L2 request count at identical HBM bytes.
// Grid capped at 2048 blocks (8 blocks/CU x 4 waves = 32 waves/CU, no tail)
// with a grid-stride loop per Guideline 11.
// Pure streaming, no reuse: nontemporal loads+stores (evict-first).

typedef float v4f __attribute__((ext_vector_type(4)));

#define W 128
#define IMG (128 * 128)

__global__ void __launch_bounds__(256) wfdm_kernel(const float* __restrict__ x,
                                                   float* __restrict__ out) {
    // work item = (plane, row_pair, col4-group)
    // planes = 16*256 = 4096, row_pairs = 64, col4 groups = 32
    // total = 4096 * 64 * 32 = 8,388,608
    const int total = 4096 * 64 * 32;
    const int nthreads = gridDim.x * blockDim.x; // 524,288 -> 16 iters/thread

    for (int tid = blockIdx.x * blockDim.x + threadIdx.x; tid < total;
         tid += nthreads) {
        const int w4  = tid & 31;         // col4 group: cols [4*w4, 4*w4+4)
        const int hp  = (tid >> 5) & 63;  // row pair: rows 2hp, 2hp+1
        const int img = tid >> 11;        // fused (batch, channel) plane

        const size_t base =
            (size_t)img * IMG + (size_t)(hp * 2) * W + (size_t)(w4 * 4);

        // rows 2hp and 2hp+1, 4 contiguous cols each
        const v4f a = __builtin_nontemporal_load(
            reinterpret_cast<const v4f*>(x + base));
        const v4f b = __builtin_nontemporal_load(
            reinterpret_cast<const v4f*>(x + base + W));

        const float s0 = (a.x + a.y + b.x + b.y) * 0.5f;
        const float s1 = (a.z + a.w + b.z + b.w) * 0.5f;

        v4f o;
        o.x = s0; o.y = s0; o.z = s1; o.w = s1;

        __builtin_nontemporal_store(o, reinterpret_cast<v4f*>(out + base));
        __builtin_nontemporal_store(o, reinterpret_cast<v4f*>(out + base + W));
    }
}

extern "C" void kernel_launch(void* const* d_in, const int* in_sizes, int n_in,
                              void* d_out, int out_size, void* d_ws, size_t ws_size,
                              hipStream_t stream) {
    const float* x = (const float*)d_in[0];
    float* out = (float*)d_out;

    const int block = 256;
    const int grid = 2048; // 8 blocks/CU on 256 CUs, grid-stride covers the rest
    wfdm_kernel<<<grid, block, 0, stream>>>(x, out);
}